// Round 10
// baseline (396.733 us; speedup 1.0000x reference)
//
#include <hip/hip_runtime.h>
#include <hip/hip_bf16.h>

typedef unsigned short u16;
typedef unsigned int u32;
typedef __attribute__((ext_vector_type(4))) unsigned short u16x4;
typedef __attribute__((ext_vector_type(8))) unsigned short u16x8;
typedef __attribute__((ext_vector_type(8))) short bf16x8;
typedef __attribute__((ext_vector_type(4))) float f32x4;

#define ROWS 2048
#define CV 768
#define VOCAB 50000
#define NPAD 50176     // 196 * 256
#define NTILES 196
#define NSEG 392       // NPAD / 128
#define NSEGP 392
#define DNB 300
#define TOTAL_IN 1671
#define KPAD1 1696
#define HD 768
#define NT 12          // K-tiles of 64 in CV=768
#define CVT_BLOCKS 2048
#define W1T_BLOCKS (53 * 24)
#define W2T_BLOCKS (24 * 24)

__device__ __forceinline__ u16 f2bf(float f) {
  union { __hip_bfloat16 h; u16 u; } x;
  x.h = __float2bfloat16(f);
  return x.u;
}

// order-preserving u16 key for bf16 bit pattern
__device__ __forceinline__ u16 bfkey(u16 u) {
  return (u & 0x8000) ? (u16)~u : (u16)(u | 0x8000);
}

__device__ __forceinline__ void gload16(const u16* g, const u16* l) {
  __builtin_amdgcn_global_load_lds(
      (const __attribute__((address_space(1))) void*)g,
      (__attribute__((address_space(3))) void*)l, 16, 0, 0);
}

__device__ __forceinline__ float block_sum256(float v, float* ws) {
#pragma unroll
  for (int off = 32; off > 0; off >>= 1) v += __shfl_xor(v, off, 64);
  int tid = threadIdx.x;
  if ((tid & 63) == 0) ws[tid >> 6] = v;
  __syncthreads();
  float s = ws[0] + ws[1] + ws[2] + ws[3];
  __syncthreads();
  return s;
}

// ---------------- fused prep: normalize | T cvt | W1 transpose | W2 transpose ----------------
__device__ __forceinline__ void transpose_tile(
    const float* __restrict__ src, u16* __restrict__ dst,
    int Ksrc, int ldk, int N, int kb, int nb, float (*tile)[33]) {
  int tx = threadIdx.x & 31, ty = threadIdx.x >> 5;  // 32 x 8
#pragma unroll
  for (int i = 0; i < 4; ++i) {
    int k = kb + ty + i * 8, n = nb + tx;
    tile[ty + i * 8][tx] = (k < Ksrc) ? src[(size_t)k * N + n] : 0.f;
  }
  __syncthreads();
#pragma unroll
  for (int i = 0; i < 4; ++i) {
    int n = nb + ty + i * 8, k = kb + tx;
    dst[(size_t)n * ldk + k] = f2bf(tile[tx][ty + i * 8]);
  }
}

__global__ __launch_bounds__(256) void prep_kernel(
    const float* __restrict__ v_seq, float* __restrict__ rinv, u16* __restrict__ q16,
    const float* __restrict__ T, u16* __restrict__ T16,
    const float* __restrict__ W1, u16* __restrict__ W1T,
    const float* __restrict__ W2, u16* __restrict__ W2T) {
  __shared__ float tile[32][33];
  int b = blockIdx.x, tid = threadIdx.x;
  if (b < ROWS) {
    float* ws = &tile[0][0];
    const float* x = v_seq + (size_t)b * CV;
    float x0 = x[tid], x1 = x[tid + 256], x2 = x[tid + 512];
    float s = block_sum256(x0 * x0 + x1 * x1 + x2 * x2, ws);
    float denom = fmaxf(sqrtf(s), 1e-12f);
    float inv = 1.0f / denom;
    u16* qb = q16 + (size_t)b * CV;
    qb[tid] = f2bf(x0 * inv); qb[tid + 256] = f2bf(x1 * inv); qb[tid + 512] = f2bf(x2 * inv);
    if (tid == 0) rinv[b] = inv;
  } else if (b < ROWS + CVT_BLOCKS) {
    int i = (b - ROWS) * 256 + tid;
    const int n4 = VOCAB * CV / 4;
    const int stride = CVT_BLOCKS * 256;
    for (; i < n4; i += stride) {
      float4 v = reinterpret_cast<const float4*>(T)[i];
      u16x4 o = {f2bf(v.x), f2bf(v.y), f2bf(v.z), f2bf(v.w)};
      reinterpret_cast<u16x4*>(T16)[i] = o;
    }
  } else if (b < ROWS + CVT_BLOCKS + W1T_BLOCKS) {
    int bb = b - ROWS - CVT_BLOCKS;
    transpose_tile(W1, W1T, TOTAL_IN, KPAD1, HD, (bb % 53) * 32, (bb / 53) * 32, tile);
  } else {
    int bb = b - ROWS - CVT_BLOCKS - W1T_BLOCKS;
    transpose_tile(W2, W2T, HD, HD, HD, (bb % 24) * 32, (bb / 24) * 32, tile);
  }
}

// =========== 256x256 score GEMM, minimal-barrier schedule (2 barriers/K-tile) ===========
// Hazard analysis: reads hit cbase, stages write nbase (double buffer) -> no
// intra-tile cross-wave hazard.  Only (a) tile boundary: all waves' first-6
// stages (B0-3,A0,A2) landed -> vmcnt(2)+barrier; (b) A1,A3 landed before
// A-hi reads -> vmcnt(4)+barrier.  sched_barrier(0) pins reads behind barriers.
__global__ __launch_bounds__(512, 2) void score_gemm_256(
    const u16* __restrict__ q16, const u16* __restrict__ T16,
    u16* __restrict__ S16, u16* __restrict__ segmax) {
  __shared__ __align__(16) u16 lds[65536];   // 128 KB: [buf][A 16KB | B 16KB] x2
  __shared__ float smx[256][4];

  int tid = threadIdx.x;
  int w = tid >> 6, lane = tid & 63;
  int wr = w >> 2, wc = w & 3;          // 2 x 4 wave grid
  int l15 = lane & 15, l4 = lane >> 4;

  // XCD-aware bijective swizzle: 1568 = 8 * 196
  int bid = blockIdx.x;
  int wg = (bid & 7) * NTILES + (bid >> 3);
  int mtile = wg & 7, ntile = wg >> 3;
  int m0 = mtile * 256, n0 = ntile * 256;

  // staging geometry
  int t8 = tid >> 3;                         // row within 64-row gload span
  int jcol = (((tid & 7) ^ (t8 & 7)) << 3);  // pre-swizzled source col (u16)
  int rowA = m0 + t8;
  int rowB0 = n0 + t8;        rowB0 = rowB0 > (VOCAB - 1) ? (VOCAB - 1) : rowB0;
  int rowB1 = n0 + 64 + t8;   rowB1 = rowB1 > (VOCAB - 1) ? (VOCAB - 1) : rowB1;
  int rowB2 = n0 + 128 + t8;  rowB2 = rowB2 > (VOCAB - 1) ? (VOCAB - 1) : rowB2;
  int rowB3 = n0 + 192 + t8;  rowB3 = rowB3 > (VOCAB - 1) ? (VOCAB - 1) : rowB3;
  int w512 = w * 512;

  // ds_read swizzled column offsets (u16 units)
  int xorv = (l15 & 7) << 4;
  int l416 = l4 << 4;
  int c0 = ((l416) ^ xorv) >> 1;
  int c1 = ((64 + l416) ^ xorv) >> 1;
  int aro = (wr * 128 + l15) * 64;        // A row base (u16)
  int bro = 16384 + (wc * 64 + l15) * 64; // B row base (u16)

  f32x4 acc[8][4];
#pragma unroll
  for (int i = 0; i < 8; ++i)
#pragma unroll
    for (int j = 0; j < 4; ++j) acc[i][j] = {0.f, 0.f, 0.f, 0.f};

  bf16x8 af[2][4], bfr[2][4];

#define STAGE_A(R0) gload16(q16 + (size_t)(rowA + (R0)) * CV + ktn + jcol, \
                            &lds[nbase + (R0) * 64 + w512])
#define STAGE_B0() gload16(T16 + (size_t)rowB0 * CV + ktn + jcol, &lds[nbase + 16384 + w512])
#define STAGE_B1() gload16(T16 + (size_t)rowB1 * CV + ktn + jcol, &lds[nbase + 16384 + 4096 + w512])
#define STAGE_B2() gload16(T16 + (size_t)rowB2 * CV + ktn + jcol, &lds[nbase + 16384 + 8192 + w512])
#define STAGE_B3() gload16(T16 + (size_t)rowB3 * CV + ktn + jcol, &lds[nbase + 16384 + 12288 + w512])

#define LDA4(MIB)                                                           \
  _Pragma("unroll") for (int ks = 0; ks < 2; ++ks)                          \
  _Pragma("unroll") for (int mi = 0; mi < 4; ++mi)                          \
    af[ks][mi] = *reinterpret_cast<const bf16x8*>(                          \
        &lds[cbase + aro + ((MIB) + mi) * 1024 + (ks ? c1 : c0)]);

#define LDB2(NIB)                                                           \
  _Pragma("unroll") for (int ks = 0; ks < 2; ++ks)                          \
  _Pragma("unroll") for (int ni = 0; ni < 2; ++ni)                          \
    bfr[ks][(NIB) + ni] = *reinterpret_cast<const bf16x8*>(                 \
        &lds[cbase + bro + ((NIB) + ni) * 1024 + (ks ? c1 : c0)]);

#define MFMAQ(MIB, NIB)                                                     \
  _Pragma("unroll") for (int mi = 0; mi < 4; ++mi)                          \
  _Pragma("unroll") for (int ni = 0; ni < 2; ++ni) {                        \
    acc[(MIB) + mi][(NIB) + ni] = __builtin_amdgcn_mfma_f32_16x16x32_bf16(  \
        af[0][mi], bfr[0][(NIB) + ni], acc[(MIB) + mi][(NIB) + ni], 0, 0, 0); \
    acc[(MIB) + mi][(NIB) + ni] = __builtin_amdgcn_mfma_f32_16x16x32_bf16(  \
        af[1][mi], bfr[1][(NIB) + ni], acc[(MIB) + mi][(NIB) + ni], 0, 0, 0); \
  }

  // ---- prologue: stage tile 0 into buf 0 (order: B0 B1 B2 B3 A0 A2 A1 A3) ----
  {
    int nbase = 0, ktn = 0;
    STAGE_B0(); STAGE_B1(); STAGE_B2(); STAGE_B3();
    STAGE_A(0); STAGE_A(128); STAGE_A(64); STAGE_A(192);
  }

  for (int t = 0; t < NT; ++t) {
    int cb = t & 1;
    int cbase = cb * 32768;
    int nbase = cbase ^ 32768;
    int ktn = ((t + 1 < NT) ? (t + 1) : t) * 64;

    // (a) tile boundary: all waves' first-6 stages of this tile landed
    asm volatile("s_waitcnt vmcnt(2)" ::: "memory");
    __builtin_amdgcn_s_barrier();
    __builtin_amdgcn_sched_barrier(0);

    LDA4(0)
    LDB2(0)
    STAGE_B0(); STAGE_B1();
    __builtin_amdgcn_s_setprio(1);
    MFMAQ(0, 0)
    __builtin_amdgcn_s_setprio(0);

    LDB2(2)
    STAGE_B2(); STAGE_B3();
    __builtin_amdgcn_s_setprio(1);
    MFMAQ(0, 2)
    __builtin_amdgcn_s_setprio(0);

    // (b) all waves' A1,A3 of this tile landed before A-hi reads
    asm volatile("s_waitcnt vmcnt(4)" ::: "memory");
    __builtin_amdgcn_s_barrier();
    __builtin_amdgcn_sched_barrier(0);

    LDA4(4)
    STAGE_A(0); STAGE_A(128);
    __builtin_amdgcn_s_setprio(1);
    MFMAQ(4, 0)
    __builtin_amdgcn_s_setprio(0);

    STAGE_A(64); STAGE_A(192);
    __builtin_amdgcn_s_setprio(1);
    MFMAQ(4, 2)
    __builtin_amdgcn_s_setprio(0);
  }
  asm volatile("s_waitcnt vmcnt(0)" ::: "memory");
  asm volatile("s_waitcnt lgkmcnt(0)" ::: "memory");
  __syncthreads();

  // ---- epilogue: bf16 S store + per-128-col segment max (padding masked) ----
#pragma unroll
  for (int mi = 0; mi < 8; ++mi)
#pragma unroll
    for (int ni = 0; ni < 4; ++ni) {
      int gr = m0 + wr * 128 + mi * 16 + l4 * 4;
      int gc = n0 + wc * 64 + ni * 16 + l15;
#pragma unroll
      for (int r = 0; r < 4; ++r)
        S16[(size_t)(gr + r) * NPAD + gc] = f2bf(acc[mi][ni][r]);
    }

#pragma unroll
  for (int mi = 0; mi < 8; ++mi)
#pragma unroll
    for (int r = 0; r < 4; ++r) {
      float v = -3e38f;
#pragma unroll
      for (int ni = 0; ni < 4; ++ni) {
        bool ok = (n0 + wc * 64 + ni * 16 + l15) < VOCAB;
        v = fmaxf(v, ok ? acc[mi][ni][r] : -3e38f);
      }
#pragma unroll
      for (int d = 1; d < 16; d <<= 1) v = fmaxf(v, __shfl_xor(v, d, 64));
      if (l15 == 0) smx[wr * 128 + mi * 16 + l4 * 4 + r][wc] = v;
    }
  __syncthreads();
  if (tid < 256) {
    float s0 = fmaxf(smx[tid][0], smx[tid][1]);
    float s1 = fmaxf(smx[tid][2], smx[tid][3]);
    segmax[(size_t)(m0 + tid) * NSEGP + 2 * ntile]     = bfkey(f2bf(s0));
    segmax[(size_t)(m0 + tid) * NSEGP + 2 * ntile + 1] = bfkey(f2bf(s1));
  }
#undef STAGE_A
#undef STAGE_B0
#undef STAGE_B1
#undef STAGE_B2
#undef STAGE_B3
#undef LDA4
#undef LDB2
#undef MFMAQ
}

// ---------------- bf16 MFMA GEMM, 64x128 tile, B^T layout — MLP ----------------
template <int ACT, int OUTBF>
__global__ __launch_bounds__(256) void gemm_bt64(
    const u16* __restrict__ A, int lda,
    const u16* __restrict__ B, int ldb, int nclamp,
    int Kdim, const float* __restrict__ bias,
    float* __restrict__ Cf, u16* __restrict__ Cb, int ldc) {
  __shared__ __align__(16) u16 Asm[64 * 32];    // 4 KB
  __shared__ __align__(16) u16 Bsm[128 * 32];   // 8 KB
  int tid = threadIdx.x;
  int w = tid >> 6, lane = tid & 63;
  int wr = w >> 1, wc = w & 1;                  // 2 x 2 wave grid
  int m0 = blockIdx.x * 64;
  int n0 = blockIdx.y * 128;
  f32x4 acc[2][4];
#pragma unroll
  for (int i = 0; i < 2; ++i)
#pragma unroll
    for (int j = 0; j < 4; ++j) acc[i][j] = {0.f, 0.f, 0.f, 0.f};

  int r0 = tid >> 2, s0 = tid & 3;              // 64 rows x 4 chunks
  int b0r = n0 + r0;       b0r = b0r > nclamp ? nclamp : b0r;
  int b1r = n0 + 64 + r0;  b1r = b1r > nclamp ? nclamp : b1r;

  for (int k0 = 0; k0 < Kdim; k0 += 32) {
    __syncthreads();
    gload16(A + (size_t)(m0 + r0) * lda + k0 + s0 * 8, Asm + w * 512);
    gload16(B + (size_t)b0r * ldb + k0 + s0 * 8, Bsm + w * 512);
    gload16(B + (size_t)b1r * ldb + k0 + s0 * 8, Bsm + 2048 + w * 512);
    __syncthreads();
    int l15 = lane & 15, l4 = lane >> 4;
    bf16x8 af[2], bfr[4];
#pragma unroll
    for (int mi = 0; mi < 2; ++mi)
      af[mi] = *reinterpret_cast<const bf16x8*>(Asm + (wr * 32 + mi * 16 + l15) * 32 + l4 * 8);
#pragma unroll
    for (int ni = 0; ni < 4; ++ni)
      bfr[ni] = *reinterpret_cast<const bf16x8*>(Bsm + (wc * 64 + ni * 16 + l15) * 32 + l4 * 8);
#pragma unroll
    for (int mi = 0; mi < 2; ++mi)
#pragma unroll
      for (int ni = 0; ni < 4; ++ni)
        acc[mi][ni] = __builtin_amdgcn_mfma_f32_16x16x32_bf16(af[mi], bfr[ni], acc[mi][ni], 0, 0, 0);
  }

  int l15 = lane & 15, l4 = lane >> 4;
#pragma unroll
  for (int mi = 0; mi < 2; ++mi) {
#pragma unroll
    for (int ni = 0; ni < 4; ++ni) {
      int gr = m0 + wr * 32 + mi * 16 + l4 * 4;
      int gc = n0 + wc * 64 + ni * 16 + l15;
      float bv = bias ? bias[gc] : 0.f;
#pragma unroll
      for (int r = 0; r < 4; ++r) {
        float x = acc[mi][ni][r] + bv;
        if (ACT) x = 0.5f * x * (1.0f + erff(x * 0.70710678118654752f));
        size_t co = (size_t)(gr + r) * ldc + gc;
        if (OUTBF) Cb[co] = f2bf(x);
        else       Cf[co] = x;
      }
    }
  }
}

// ---------------- fused: segment-select top-16 -> fp32 rescore -> top-3 -> concat ----------------
__global__ __launch_bounds__(256) void select_kernel(
    const u16* __restrict__ segmax, const u16* __restrict__ S,
    const float* __restrict__ v_seq, const float* __restrict__ rinv,
    const float* __restrict__ T, const float* __restrict__ nb,
    u16* __restrict__ c16) {
  __shared__ u32 skey[448];
  __shared__ u32 winners[16];
  __shared__ u32 cl[256][16];
  __shared__ int scand[16];
  __shared__ float sex[16];
  __shared__ float sval[3];
  __shared__ int sidx[3];
  int row = blockIdx.x, tid = threadIdx.x;

  // ---- phase 1: top-16 segments by (max desc, segidx asc) ----
  if (tid < 224) {
#pragma unroll
    for (int j = 0; j < 2; ++j) {
      int s = tid * 2 + j;
      u32 k = 0;
      if (s < NSEG) k = ((u32)segmax[(size_t)row * NSEGP + s] << 9) | (u32)(511 - s);
      skey[s] = k;
    }
  }
  __syncthreads();

  if (tid < 64) {
    u32 v[7];
#pragma unroll
    for (int j = 0; j < 7; ++j) v[j] = skey[tid + 64 * j];
#pragma unroll
    for (int rd = 0; rd < 16; ++rd) {
      u32 m = v[0];
#pragma unroll
      for (int j = 1; j < 7; ++j) m = (v[j] > m) ? v[j] : m;
#pragma unroll
      for (int d = 1; d < 64; d <<= 1) {
        u32 o = (u32)__shfl_xor((int)m, d, 64);
        m = (o > m) ? o : m;
      }
#pragma unroll
      for (int j = 0; j < 7; ++j) v[j] = (v[j] == m) ? 0u : v[j];
      if (tid == 0) winners[rd] = m;
    }
  }
  __syncthreads();

  // ---- phase 2: gather 16 segments, exact top-16 values ----
  int wi = tid >> 4, off = (tid & 15) * 8;
  int seg = 511 - (int)(winners[wi] & 511);
  const u16* Sr = S + (size_t)row * NPAD + seg * 128 + off;
  u16x8 vv = *reinterpret_cast<const u16x8*>(Sr);
  u32 ck[8];
  int gbase = seg * 128 + off;
#pragma unroll
  for (int jj = 0; jj < 8; ++jj) {
    int g = gbase + jj;
    u32 c = ((u32)bfkey(vv[jj]) << 16) | (u32)(0xFFFF - g);
    ck[jj] = (g >= VOCAB) ? 0u : c;
  }
#define CE(i, j) { u32 a = ck[i], b = ck[j]; ck[i] = a > b ? a : b; ck[j] = a > b ? b : a; }
  CE(0,1) CE(2,3) CE(4,5) CE(6,7)
  CE(0,2) CE(1,3) CE(4,6) CE(5,7)
  CE(1,2) CE(5,6)
  CE(0,4) CE(1,5) CE(2,6) CE(3,7)
  CE(2,4) CE(3,5)
  CE(1,2) CE(3,4) CE(5,6)
#undef CE
#pragma unroll
  for (int k = 0; k < 8; ++k) cl[tid][k] = ck[k];
#pragma unroll
  for (int k = 8; k < 16; ++k) cl[tid][k] = 0u;
  __syncthreads();

  for (int s = 128; s >= 1; s >>= 1) {
    if (tid < s) {
      u32 ov[16];
      int pa = 0, pb = 0;
#pragma unroll
      for (int k = 0; k < 16; ++k) {
        u32 va = cl[tid][pa], vb = cl[tid + s][pb];
        bool ta = va >= vb;
        ov[k] = ta ? va : vb;
        pa += ta ? 1 : 0;
        pb += ta ? 0 : 1;
      }
#pragma unroll
      for (int k = 0; k < 16; ++k) cl[tid][k] = ov[k];
    }
    __syncthreads();
  }
  if (tid < 16) scand[tid] = 0xFFFF - (int)(cl[0][tid] & 0xFFFF);
  __syncthreads();

  // ---- phase 3: exact fp32 rescore of 16 candidates ----
  int wv = tid >> 6, lane = tid & 63;
  const float* __restrict__ qr = v_seq + (size_t)row * CV;
  float ri = rinv[row];
#pragma unroll
  for (int c0 = 0; c0 < 4; ++c0) {
    int c = wv + c0 * 4;
    int n = scand[c];
    const float* tr = T + (size_t)n * CV;
    float part = 0.f;
    int kb = lane * 12;
#pragma unroll
    for (int j3 = 0; j3 < 3; ++j3) {
      float4 a = *reinterpret_cast<const float4*>(tr + kb + j3 * 4);
      float4 b = *reinterpret_cast<const float4*>(qr + kb + j3 * 4);
      part += a.x * b.x + a.y * b.y + a.z * b.z + a.w * b.w;
    }
#pragma unroll
    for (int off2 = 32; off2 >= 1; off2 >>= 1) part += __shfl_xor(part, off2, 64);
    if (lane == 0) sex[c] = part * ri;
  }
  __syncthreads();
  if (tid == 0) {
    float xv[16]; int xi[16];
#pragma unroll
    for (int c = 0; c < 16; ++c) { xv[c] = sex[c]; xi[c] = scand[c]; }
    for (int t = 0; t < 3; ++t) {
      float bv = -__builtin_inff(); int bi = 0x7fffffff, bc = -1;
#pragma unroll
      for (int c = 0; c < 16; ++c) {
        if (xi[c] < 0) continue;
        if (xv[c] > bv || (xv[c] == bv && xi[c] < bi)) { bv = xv[c]; bi = xi[c]; bc = c; }
      }
      sval[t] = bv; sidx[t] = bi;
      xi[bc] = -1;
    }
  }
  __syncthreads();

  // ---- phase 4: build combined row (bf16, padded to KPAD1) ----
  u16* c = c16 + (size_t)row * KPAD1;
  if (tid < 192) {
    float4 v = *reinterpret_cast<const float4*>(qr + tid * 4);
    u16x4 o = {f2bf(v.x), f2bf(v.y), f2bf(v.z), f2bf(v.w)};
    *reinterpret_cast<u16x4*>(c + tid * 4) = o;
  }
  int i0 = sidx[0], i1 = sidx[1], i2 = sidx[2];
  if (tid < 75) {
    float4 v = *reinterpret_cast<const float4*>(nb + (size_t)i0 * DNB + tid * 4);
    u16x4 o = {f2bf(v.x), f2bf(v.y), f2bf(v.z), f2bf(v.w)};
    *reinterpret_cast<u16x4*>(c + CV + tid * 4) = o;
    v = *reinterpret_cast<const float4*>(nb + (size_t)i1 * DNB + tid * 4);
    o = {f2bf(v.x), f2bf(v.y), f2bf(v.z), f2bf(v.w)};
    *reinterpret_cast<u16x4*>(c + CV + DNB + tid * 4) = o;
    v = *reinterpret_cast<const float4*>(nb + (size_t)i2 * DNB + tid * 4);
    o = {f2bf(v.x), f2bf(v.y), f2bf(v.z), f2bf(v.w)};
    *reinterpret_cast<u16x4*>(c + CV + 2 * DNB + tid * 4) = o;
  }
  if (tid < 28) {
    int o = CV + 3 * DNB + tid;
    c[o] = (tid < 3) ? f2bf(sval[tid]) : (u16)0;
  }
}

// ---------------- in-place LayerNorm ----------------
__global__ __launch_bounds__(256) void layernorm_kernel(float* __restrict__ C) {
  __shared__ float ws[4];
  int row = blockIdx.x, tid = threadIdx.x;
  float* x = C + (size_t)row * CV;
  float x0 = x[tid], x1 = x[tid + 256], x2 = x[tid + 512];
  float mu = block_sum256(x0 + x1 + x2, ws) * (1.0f / 768.0f);
  float d0 = x0 - mu, d1 = x1 - mu, d2 = x2 - mu;
  float var = block_sum256(d0 * d0 + d1 * d1 + d2 * d2, ws) * (1.0f / 768.0f);
  float inv = 1.0f / sqrtf(var + 1e-5f);
  x[tid] = d0 * inv; x[tid + 256] = d1 * inv; x[tid + 512] = d2 * inv;
}

extern "C" void kernel_launch(void* const* d_in, const int* in_sizes, int n_in,
                              void* d_out, int out_size, void* d_ws, size_t ws_size,
                              hipStream_t stream) {
  const float* v_seq = (const float*)d_in[0];
  const float* T = (const float*)d_in[1];
  const float* nb = (const float*)d_in[2];
  const float* W1 = (const float*)d_in[3];
  const float* b1 = (const float*)d_in[4];
  const float* W2 = (const float*)d_in[5];
  const float* b2 = (const float*)d_in[6];
  float* out = (float*)d_out;

  char* base = (char*)d_ws;
  size_t off = 0;
  auto alloc = [&](size_t bytes) -> void* {
    void* p = base + off;
    off += (bytes + 255) & ~(size_t)255;
    return p;
  };
  float* rinv = (float*)alloc((size_t)ROWS * 4);
  u16* q16   = (u16*)alloc((size_t)ROWS * CV * 2);
  u16* T16   = (u16*)alloc((size_t)VOCAB * CV * 2);
  u16* c16   = (u16*)alloc((size_t)ROWS * KPAD1 * 2);
  u16* h16   = (u16*)alloc((size_t)ROWS * HD * 2);
  u16* W1T   = (u16*)alloc((size_t)HD * KPAD1 * 2);
  u16* W2T   = (u16*)alloc((size_t)HD * HD * 2);
  u16* segmaxb = (u16*)alloc((size_t)ROWS * NSEGP * 2);
  u16* S16   = (u16*)alloc((size_t)ROWS * NPAD * 2);  // 205.5 MB

  prep_kernel<<<ROWS + CVT_BLOCKS + W1T_BLOCKS + W2T_BLOCKS, 256, 0, stream>>>(
      v_seq, rinv, q16, T, T16, W1, W1T, W2, W2T);
  score_gemm_256<<<8 * NTILES, 512, 0, stream>>>(q16, T16, S16, segmaxb);
  select_kernel<<<ROWS, 256, 0, stream>>>(segmaxb, S16, v_seq, rinv, T, nb, c16);
  gemm_bt64<1, 1><<<dim3(ROWS / 64, HD / 128), 256, 0, stream>>>(
      c16, KPAD1, W1T, KPAD1, HD - 1, KPAD1, b1, nullptr, h16, HD);
  gemm_bt64<0, 0><<<dim3(ROWS / 64, HD / 128), 256, 0, stream>>>(
      h16, HD, W2T, HD, HD - 1, HD, b2, out, nullptr, HD);
  layernorm_kernel<<<ROWS, 256, 0, stream>>>(out);
}

// Round 11
// 368.011 us; speedup vs baseline: 1.0780x; 1.0780x over previous
//
#include <hip/hip_runtime.h>
#include <hip/hip_bf16.h>

typedef unsigned short u16;
typedef unsigned int u32;
typedef __attribute__((ext_vector_type(4))) unsigned short u16x4;
typedef __attribute__((ext_vector_type(8))) unsigned short u16x8;
typedef __attribute__((ext_vector_type(8))) short bf16x8;
typedef __attribute__((ext_vector_type(4))) float f32x4;

#define ROWS 2048
#define CV 768
#define VOCAB 50000
#define NPAD 50176     // 392 * 128
#define NTILES 392     // 128-wide output tiles
#define NSEG 392
#define NSEGP 392
#define DNB 300
#define TOTAL_IN 1671
#define KPAD1 1696
#define HD 768
#define NT2 24         // K-tiles of 32 in CV=768
#define CVT_BLOCKS 2048
#define W1T_BLOCKS (53 * 24)
#define W2T_BLOCKS (24 * 24)

__device__ __forceinline__ u16 f2bf(float f) {
  union { __hip_bfloat16 h; u16 u; } x;
  x.h = __float2bfloat16(f);
  return x.u;
}

// order-preserving u16 key for bf16 bit pattern
__device__ __forceinline__ u16 bfkey(u16 u) {
  return (u & 0x8000) ? (u16)~u : (u16)(u | 0x8000);
}

__device__ __forceinline__ void gload16(const u16* g, const u16* l) {
  __builtin_amdgcn_global_load_lds(
      (const __attribute__((address_space(1))) void*)g,
      (__attribute__((address_space(3))) void*)l, 16, 0, 0);
}

__device__ __forceinline__ float block_sum256(float v, float* ws) {
#pragma unroll
  for (int off = 32; off > 0; off >>= 1) v += __shfl_xor(v, off, 64);
  int tid = threadIdx.x;
  if ((tid & 63) == 0) ws[tid >> 6] = v;
  __syncthreads();
  float s = ws[0] + ws[1] + ws[2] + ws[3];
  __syncthreads();
  return s;
}

// ---------------- fused prep: normalize | T cvt | W1 transpose | W2 transpose ----------------
__device__ __forceinline__ void transpose_tile(
    const float* __restrict__ src, u16* __restrict__ dst,
    int Ksrc, int ldk, int N, int kb, int nb, float (*tile)[33]) {
  int tx = threadIdx.x & 31, ty = threadIdx.x >> 5;  // 32 x 8
#pragma unroll
  for (int i = 0; i < 4; ++i) {
    int k = kb + ty + i * 8, n = nb + tx;
    tile[ty + i * 8][tx] = (k < Ksrc) ? src[(size_t)k * N + n] : 0.f;
  }
  __syncthreads();
#pragma unroll
  for (int i = 0; i < 4; ++i) {
    int n = nb + ty + i * 8, k = kb + tx;
    dst[(size_t)n * ldk + k] = f2bf(tile[tx][ty + i * 8]);
  }
}

__global__ __launch_bounds__(256) void prep_kernel(
    const float* __restrict__ v_seq, float* __restrict__ rinv, u16* __restrict__ q16,
    const float* __restrict__ T, u16* __restrict__ T16,
    const float* __restrict__ W1, u16* __restrict__ W1T,
    const float* __restrict__ W2, u16* __restrict__ W2T) {
  __shared__ float tile[32][33];
  int b = blockIdx.x, tid = threadIdx.x;
  if (b < ROWS) {
    float* ws = &tile[0][0];
    const float* x = v_seq + (size_t)b * CV;
    float x0 = x[tid], x1 = x[tid + 256], x2 = x[tid + 512];
    float s = block_sum256(x0 * x0 + x1 * x1 + x2 * x2, ws);
    float denom = fmaxf(sqrtf(s), 1e-12f);
    float inv = 1.0f / denom;
    u16* qb = q16 + (size_t)b * CV;
    qb[tid] = f2bf(x0 * inv); qb[tid + 256] = f2bf(x1 * inv); qb[tid + 512] = f2bf(x2 * inv);
    if (tid == 0) rinv[b] = inv;
  } else if (b < ROWS + CVT_BLOCKS) {
    int i = (b - ROWS) * 256 + tid;
    const int n4 = VOCAB * CV / 4;
    const int stride = CVT_BLOCKS * 256;
    for (; i < n4; i += stride) {
      float4 v = reinterpret_cast<const float4*>(T)[i];
      u16x4 o = {f2bf(v.x), f2bf(v.y), f2bf(v.z), f2bf(v.w)};
      reinterpret_cast<u16x4*>(T16)[i] = o;
    }
  } else if (b < ROWS + CVT_BLOCKS + W1T_BLOCKS) {
    int bb = b - ROWS - CVT_BLOCKS;
    transpose_tile(W1, W1T, TOTAL_IN, KPAD1, HD, (bb % 53) * 32, (bb / 53) * 32, tile);
  } else {
    int bb = b - ROWS - CVT_BLOCKS - W1T_BLOCKS;
    transpose_tile(W2, W2T, HD, HD, HD, (bb % 24) * 32, (bb / 24) * 32, tile);
  }
}

// =========== 256x128 BK=32 score GEMM, 2 blocks/CU (occupancy-first) ===========
// Per wave (4x2 grid): 64x64 output, acc 4x4 f32x4 (64 regs) -> ~120 VGPR/wave,
// LDS 2x24KB dbuf + smx = 52KB -> 2 blocks/CU. Per K-tile: 3 gloads (A0,A1,B),
// 8 ds_read_b128, 16 MFMA. Counted syncs: issue order A0,A1,B =>
// boundary vmcnt(1) (A landed), after restage-A vmcnt(2) (B landed).
__global__ __launch_bounds__(512, 4) void score_gemm_bk32(
    const u16* __restrict__ q16, const u16* __restrict__ T16,
    u16* __restrict__ S16, u16* __restrict__ segmax) {
  __shared__ __align__(16) u16 lds[24576];   // 48 KB: 2 x (A 16KB | B 8KB)
  __shared__ float smx[256][2];

  int tid = threadIdx.x;
  int w = tid >> 6, lane = tid & 63;
  int wr = w >> 1, wc = w & 1;          // 4 x 2 wave grid
  int l15 = lane & 15, l4 = lane >> 4;

  // XCD-aware bijective swizzle: 3136 = 8 * 392
  int bid = blockIdx.x;
  int wg = (bid & 7) * NTILES + (bid >> 3);
  int mtile = wg & 7, ntile = wg >> 3;
  int m0 = mtile * 256, n0 = ntile * 128;

  // staging geometry: per gload unit = 128 rows x 32 K; row = tid>>2, chunk = tid&3
  int t4 = tid >> 2;
  int jcol = (((tid & 3) ^ (t4 & 3)) << 3);  // pre-swizzled source col (u16)
  int tid8 = tid * 8;                        // linear LDS dest (u16)
  const u16* pA0 = q16 + (size_t)(m0 + t4) * CV + jcol;
  const u16* pA1 = q16 + (size_t)(m0 + 128 + t4) * CV + jcol;
  int rowB = n0 + t4; rowB = rowB > (VOCAB - 1) ? (VOCAB - 1) : rowB;
  const u16* pB = T16 + (size_t)rowB * CV + jcol;

  // ds_read swizzled chunk offset (u16): phys chunk = l4 ^ (row&3), row&3 == l15&3
  int coff = ((l4 ^ (l15 & 3)) << 3);
  int aro = (wr * 64 + l15) * 32;            // A row base (u16)
  int bro = 8192 + (wc * 64 + l15) * 32;     // B row base (u16)

  f32x4 acc[4][4];
#pragma unroll
  for (int i = 0; i < 4; ++i)
#pragma unroll
    for (int j = 0; j < 4; ++j) acc[i][j] = {0.f, 0.f, 0.f, 0.f};

  bf16x8 af[4], bfr[4];

#define STAGE_A0() gload16(pA0 + ktn, &lds[nbase + tid8])
#define STAGE_A1() gload16(pA1 + ktn, &lds[nbase + 4096 + tid8])
#define STAGE_B()  gload16(pB + ktn, &lds[nbase + 8192 + tid8])

  // ---- prologue: stage tile 0 (order: A0 A1 B) ----
  {
    int nbase = 0, ktn = 0;
    STAGE_A0(); STAGE_A1(); STAGE_B();
  }

  for (int t = 0; t < NT2; ++t) {
    int cbase = (t & 1) * 12288;
    int nbase = cbase ^ 12288;
    int ktn = ((t + 1 < NT2) ? (t + 1) : t) * 32;

    // boundary: this tile's A0,A1 landed (oldest 2 of 3 outstanding), all waves
    asm volatile("s_waitcnt vmcnt(1)" ::: "memory");
    __builtin_amdgcn_s_barrier();
    __builtin_amdgcn_sched_barrier(0);

#pragma unroll
    for (int mi = 0; mi < 4; ++mi)
      af[mi] = *reinterpret_cast<const bf16x8*>(&lds[cbase + aro + mi * 512 + coff]);
    STAGE_A0(); STAGE_A1();

    // this tile's B landed (oldest of 3 outstanding), all waves
    asm volatile("s_waitcnt vmcnt(2)" ::: "memory");
    __builtin_amdgcn_s_barrier();
    __builtin_amdgcn_sched_barrier(0);

#pragma unroll
    for (int ni = 0; ni < 4; ++ni)
      bfr[ni] = *reinterpret_cast<const bf16x8*>(&lds[cbase + bro + ni * 512 + coff]);
    STAGE_B();

    __builtin_amdgcn_s_setprio(1);
#pragma unroll
    for (int mi = 0; mi < 4; ++mi)
#pragma unroll
      for (int ni = 0; ni < 4; ++ni)
        acc[mi][ni] = __builtin_amdgcn_mfma_f32_16x16x32_bf16(af[mi], bfr[ni], acc[mi][ni], 0, 0, 0);
    __builtin_amdgcn_s_setprio(0);
  }
  asm volatile("s_waitcnt vmcnt(0)" ::: "memory");
  asm volatile("s_waitcnt lgkmcnt(0)" ::: "memory");
  __syncthreads();

  // ---- epilogue: bf16 S store + per-tile (128-col) segment max ----
#pragma unroll
  for (int mi = 0; mi < 4; ++mi)
#pragma unroll
    for (int ni = 0; ni < 4; ++ni) {
      int gr = m0 + wr * 64 + mi * 16 + l4 * 4;
      int gc = n0 + wc * 64 + ni * 16 + l15;
#pragma unroll
      for (int r = 0; r < 4; ++r)
        S16[(size_t)(gr + r) * NPAD + gc] = f2bf(acc[mi][ni][r]);
    }

#pragma unroll
  for (int mi = 0; mi < 4; ++mi)
#pragma unroll
    for (int r = 0; r < 4; ++r) {
      float v = -3e38f;
#pragma unroll
      for (int ni = 0; ni < 4; ++ni) {
        bool ok = (n0 + wc * 64 + ni * 16 + l15) < VOCAB;
        v = fmaxf(v, ok ? acc[mi][ni][r] : -3e38f);
      }
#pragma unroll
      for (int d = 1; d < 16; d <<= 1) v = fmaxf(v, __shfl_xor(v, d, 64));
      if (l15 == 0) smx[wr * 64 + mi * 16 + l4 * 4 + r][wc] = v;
    }
  __syncthreads();
  if (tid < 256) {
    float s0 = fmaxf(smx[tid][0], smx[tid][1]);
    segmax[(size_t)(m0 + tid) * NSEGP + ntile] = bfkey(f2bf(s0));
  }
#undef STAGE_A0
#undef STAGE_A1
#undef STAGE_B
}

// ---------------- bf16 MFMA GEMM, 64x128 tile, B^T layout — MLP ----------------
template <int ACT, int OUTBF>
__global__ __launch_bounds__(256) void gemm_bt64(
    const u16* __restrict__ A, int lda,
    const u16* __restrict__ B, int ldb, int nclamp,
    int Kdim, const float* __restrict__ bias,
    float* __restrict__ Cf, u16* __restrict__ Cb, int ldc) {
  __shared__ __align__(16) u16 Asm[64 * 32];    // 4 KB
  __shared__ __align__(16) u16 Bsm[128 * 32];   // 8 KB
  int tid = threadIdx.x;
  int w = tid >> 6, lane = tid & 63;
  int wr = w >> 1, wc = w & 1;                  // 2 x 2 wave grid
  int m0 = blockIdx.x * 64;
  int n0 = blockIdx.y * 128;
  f32x4 acc[2][4];
#pragma unroll
  for (int i = 0; i < 2; ++i)
#pragma unroll
    for (int j = 0; j < 4; ++j) acc[i][j] = {0.f, 0.f, 0.f, 0.f};

  int r0 = tid >> 2, s0 = tid & 3;              // 64 rows x 4 chunks
  int b0r = n0 + r0;       b0r = b0r > nclamp ? nclamp : b0r;
  int b1r = n0 + 64 + r0;  b1r = b1r > nclamp ? nclamp : b1r;

  for (int k0 = 0; k0 < Kdim; k0 += 32) {
    __syncthreads();
    gload16(A + (size_t)(m0 + r0) * lda + k0 + s0 * 8, Asm + w * 512);
    gload16(B + (size_t)b0r * ldb + k0 + s0 * 8, Bsm + w * 512);
    gload16(B + (size_t)b1r * ldb + k0 + s0 * 8, Bsm + 2048 + w * 512);
    __syncthreads();
    int l15 = lane & 15, l4 = lane >> 4;
    bf16x8 af[2], bfr[4];
#pragma unroll
    for (int mi = 0; mi < 2; ++mi)
      af[mi] = *reinterpret_cast<const bf16x8*>(Asm + (wr * 32 + mi * 16 + l15) * 32 + l4 * 8);
#pragma unroll
    for (int ni = 0; ni < 4; ++ni)
      bfr[ni] = *reinterpret_cast<const bf16x8*>(Bsm + (wc * 64 + ni * 16 + l15) * 32 + l4 * 8);
#pragma unroll
    for (int mi = 0; mi < 2; ++mi)
#pragma unroll
      for (int ni = 0; ni < 4; ++ni)
        acc[mi][ni] = __builtin_amdgcn_mfma_f32_16x16x32_bf16(af[mi], bfr[ni], acc[mi][ni], 0, 0, 0);
  }

  int l15 = lane & 15, l4 = lane >> 4;
#pragma unroll
  for (int mi = 0; mi < 2; ++mi) {
#pragma unroll
    for (int ni = 0; ni < 4; ++ni) {
      int gr = m0 + wr * 32 + mi * 16 + l4 * 4;
      int gc = n0 + wc * 64 + ni * 16 + l15;
      float bv = bias ? bias[gc] : 0.f;
#pragma unroll
      for (int r = 0; r < 4; ++r) {
        float x = acc[mi][ni][r] + bv;
        if (ACT) x = 0.5f * x * (1.0f + erff(x * 0.70710678118654752f));
        size_t co = (size_t)(gr + r) * ldc + gc;
        if (OUTBF) Cb[co] = f2bf(x);
        else       Cf[co] = x;
      }
    }
  }
}

// ---------------- fused: segment-select top-16 -> fp32 rescore -> top-3 -> concat ----------------
__global__ __launch_bounds__(256) void select_kernel(
    const u16* __restrict__ segmax, const u16* __restrict__ S,
    const float* __restrict__ v_seq, const float* __restrict__ rinv,
    const float* __restrict__ T, const float* __restrict__ nb,
    u16* __restrict__ c16) {
  __shared__ u32 skey[448];
  __shared__ u32 winners[16];
  __shared__ u32 cl[256][16];
  __shared__ int scand[16];
  __shared__ float sex[16];
  __shared__ float sval[3];
  __shared__ int sidx[3];
  int row = blockIdx.x, tid = threadIdx.x;

  // ---- phase 1: top-16 segments by (max desc, segidx asc) ----
  if (tid < 224) {
#pragma unroll
    for (int j = 0; j < 2; ++j) {
      int s = tid * 2 + j;
      u32 k = 0;
      if (s < NSEG) k = ((u32)segmax[(size_t)row * NSEGP + s] << 9) | (u32)(511 - s);
      skey[s] = k;
    }
  }
  __syncthreads();

  if (tid < 64) {
    u32 v[7];
#pragma unroll
    for (int j = 0; j < 7; ++j) v[j] = skey[tid + 64 * j];
#pragma unroll
    for (int rd = 0; rd < 16; ++rd) {
      u32 m = v[0];
#pragma unroll
      for (int j = 1; j < 7; ++j) m = (v[j] > m) ? v[j] : m;
#pragma unroll
      for (int d = 1; d < 64; d <<= 1) {
        u32 o = (u32)__shfl_xor((int)m, d, 64);
        m = (o > m) ? o : m;
      }
#pragma unroll
      for (int j = 0; j < 7; ++j) v[j] = (v[j] == m) ? 0u : v[j];
      if (tid == 0) winners[rd] = m;
    }
  }
  __syncthreads();

  // ---- phase 2: gather 16 segments, exact top-16 values ----
  int wi = tid >> 4, off = (tid & 15) * 8;
  int seg = 511 - (int)(winners[wi] & 511);
  const u16* Sr = S + (size_t)row * NPAD + seg * 128 + off;
  u16x8 vv = *reinterpret_cast<const u16x8*>(Sr);
  u32 ck[8];
  int gbase = seg * 128 + off;
#pragma unroll
  for (int jj = 0; jj < 8; ++jj) {
    int g = gbase + jj;
    u32 c = ((u32)bfkey(vv[jj]) << 16) | (u32)(0xFFFF - g);
    ck[jj] = (g >= VOCAB) ? 0u : c;
  }
#define CE(i, j) { u32 a = ck[i], b = ck[j]; ck[i] = a > b ? a : b; ck[j] = a > b ? b : a; }
  CE(0,1) CE(2,3) CE(4,5) CE(6,7)
  CE(0,2) CE(1,3) CE(4,6) CE(5,7)
  CE(1,2) CE(5,6)
  CE(0,4) CE(1,5) CE(2,6) CE(3,7)
  CE(2,4) CE(3,5)
  CE(1,2) CE(3,4) CE(5,6)
#undef CE
#pragma unroll
  for (int k = 0; k < 8; ++k) cl[tid][k] = ck[k];
#pragma unroll
  for (int k = 8; k < 16; ++k) cl[tid][k] = 0u;
  __syncthreads();

  for (int s = 128; s >= 1; s >>= 1) {
    if (tid < s) {
      u32 ov[16];
      int pa = 0, pb = 0;
#pragma unroll
      for (int k = 0; k < 16; ++k) {
        u32 va = cl[tid][pa], vb = cl[tid + s][pb];
        bool ta = va >= vb;
        ov[k] = ta ? va : vb;
        pa += ta ? 1 : 0;
        pb += ta ? 0 : 1;
      }
#pragma unroll
      for (int k = 0; k < 16; ++k) cl[tid][k] = ov[k];
    }
    __syncthreads();
  }
  if (tid < 16) scand[tid] = 0xFFFF - (int)(cl[0][tid] & 0xFFFF);
  __syncthreads();

  // ---- phase 3: exact fp32 rescore of 16 candidates ----
  int wv = tid >> 6, lane = tid & 63;
  const float* __restrict__ qr = v_seq + (size_t)row * CV;
  float ri = rinv[row];
#pragma unroll
  for (int c0 = 0; c0 < 4; ++c0) {
    int c = wv + c0 * 4;
    int n = scand[c];
    const float* tr = T + (size_t)n * CV;
    float part = 0.f;
    int kb = lane * 12;
#pragma unroll
    for (int j3 = 0; j3 < 3; ++j3) {
      float4 a = *reinterpret_cast<const float4*>(tr + kb + j3 * 4);
      float4 b = *reinterpret_cast<const float4*>(qr + kb + j3 * 4);
      part += a.x * b.x + a.y * b.y + a.z * b.z + a.w * b.w;
    }
#pragma unroll
    for (int off2 = 32; off2 >= 1; off2 >>= 1) part += __shfl_xor(part, off2, 64);
    if (lane == 0) sex[c] = part * ri;
  }
  __syncthreads();
  if (tid == 0) {
    float xv[16]; int xi[16];
#pragma unroll
    for (int c = 0; c < 16; ++c) { xv[c] = sex[c]; xi[c] = scand[c]; }
    for (int t = 0; t < 3; ++t) {
      float bv = -__builtin_inff(); int bi = 0x7fffffff, bc = -1;
#pragma unroll
      for (int c = 0; c < 16; ++c) {
        if (xi[c] < 0) continue;
        if (xv[c] > bv || (xv[c] == bv && xi[c] < bi)) { bv = xv[c]; bi = xi[c]; bc = c; }
      }
      sval[t] = bv; sidx[t] = bi;
      xi[bc] = -1;
    }
  }
  __syncthreads();

  // ---- phase 4: build combined row (bf16, padded to KPAD1) ----
  u16* c = c16 + (size_t)row * KPAD1;
  if (tid < 192) {
    float4 v = *reinterpret_cast<const float4*>(qr + tid * 4);
    u16x4 o = {f2bf(v.x), f2bf(v.y), f2bf(v.z), f2bf(v.w)};
    *reinterpret_cast<u16x4*>(c + tid * 4) = o;
  }
  int i0 = sidx[0], i1 = sidx[1], i2 = sidx[2];
  if (tid < 75) {
    float4 v = *reinterpret_cast<const float4*>(nb + (size_t)i0 * DNB + tid * 4);
    u16x4 o = {f2bf(v.x), f2bf(v.y), f2bf(v.z), f2bf(v.w)};
    *reinterpret_cast<u16x4*>(c + CV + tid * 4) = o;
    v = *reinterpret_cast<const float4*>(nb + (size_t)i1 * DNB + tid * 4);
    o = {f2bf(v.x), f2bf(v.y), f2bf(v.z), f2bf(v.w)};
    *reinterpret_cast<u16x4*>(c + CV + DNB + tid * 4) = o;
    v = *reinterpret_cast<const float4*>(nb + (size_t)i2 * DNB + tid * 4);
    o = {f2bf(v.x), f2bf(v.y), f2bf(v.z), f2bf(v.w)};
    *reinterpret_cast<u16x4*>(c + CV + 2 * DNB + tid * 4) = o;
  }
  if (tid < 28) {
    int o = CV + 3 * DNB + tid;
    c[o] = (tid < 3) ? f2bf(sval[tid]) : (u16)0;
  }
}

// ---------------- in-place LayerNorm ----------------
__global__ __launch_bounds__(256) void layernorm_kernel(float* __restrict__ C) {
  __shared__ float ws[4];
  int row = blockIdx.x, tid = threadIdx.x;
  float* x = C + (size_t)row * CV;
  float x0 = x[tid], x1 = x[tid + 256], x2 = x[tid + 512];
  float mu = block_sum256(x0 + x1 + x2, ws) * (1.0f / 768.0f);
  float d0 = x0 - mu, d1 = x1 - mu, d2 = x2 - mu;
  float var = block_sum256(d0 * d0 + d1 * d1 + d2 * d2, ws) * (1.0f / 768.0f);
  float inv = 1.0f / sqrtf(var + 1e-5f);
  x[tid] = d0 * inv; x[tid + 256] = d1 * inv; x[tid + 512] = d2 * inv;
}

extern "C" void kernel_launch(void* const* d_in, const int* in_sizes, int n_in,
                              void* d_out, int out_size, void* d_ws, size_t ws_size,
                              hipStream_t stream) {
  const float* v_seq = (const float*)d_in[0];
  const float* T = (const float*)d_in[1];
  const float* nb = (const float*)d_in[2];
  const float* W1 = (const float*)d_in[3];
  const float* b1 = (const float*)d_in[4];
  const float* W2 = (const float*)d_in[5];
  const float* b2 = (const float*)d_in[6];
  float* out = (float*)d_out;

  char* base = (char*)d_ws;
  size_t off = 0;
  auto alloc = [&](size_t bytes) -> void* {
    void* p = base + off;
    off += (bytes + 255) & ~(size_t)255;
    return p;
  };
  float* rinv = (float*)alloc((size_t)ROWS * 4);
  u16* q16   = (u16*)alloc((size_t)ROWS * CV * 2);
  u16* T16   = (u16*)alloc((size_t)VOCAB * CV * 2);
  u16* c16   = (u16*)alloc((size_t)ROWS * KPAD1 * 2);
  u16* h16   = (u16*)alloc((size_t)ROWS * HD * 2);
  u16* W1T   = (u16*)alloc((size_t)HD * KPAD1 * 2);
  u16* W2T   = (u16*)alloc((size_t)HD * HD * 2);
  u16* segmaxb = (u16*)alloc((size_t)ROWS * NSEGP * 2);
  u16* S16   = (u16*)alloc((size_t)ROWS * NPAD * 2);  // 205.5 MB

  prep_kernel<<<ROWS + CVT_BLOCKS + W1T_BLOCKS + W2T_BLOCKS, 256, 0, stream>>>(
      v_seq, rinv, q16, T, T16, W1, W1T, W2, W2T);
  score_gemm_bk32<<<8 * NTILES, 512, 0, stream>>>(q16, T16, S16, segmaxb);
  select_kernel<<<ROWS, 256, 0, stream>>>(segmaxb, S16, v_seq, rinv, T, nb, c16);
  gemm_bt64<1, 1><<<dim3(ROWS / 64, HD / 128), 256, 0, stream>>>(
      c16, KPAD1, W1T, KPAD1, HD - 1, KPAD1, b1, nullptr, h16, HD);
  gemm_bt64<0, 0><<<dim3(ROWS / 64, HD / 128), 256, 0, stream>>>(
      h16, HD, W2T, HD, HD - 1, HD, b2, out, nullptr, HD);
  layernorm_kernel<<<ROWS, 256, 0, stream>>>(out);
}